// Round 6
// baseline (348.861 us; speedup 1.0000x reference)
//
#include <hip/hip_runtime.h>

typedef __attribute__((ext_vector_type(8)))  short  short8;
typedef __attribute__((ext_vector_type(4)))  float  float4v;
typedef __attribute__((ext_vector_type(16))) float  float16v;

constexpr int HH = 256, WW = 256;
constexpr int PD = 258;                 // padded spatial dim
constexpr size_t HWsz = (size_t)HH * WW;

__device__ inline unsigned short f2bf(float f) {
    unsigned int u = __builtin_bit_cast(unsigned int, f);
    u += 0x7FFFu + ((u >> 16) & 1u);
    return (unsigned short)(u >> 16);
}
__device__ inline float bfhalf(unsigned int w, int hi) {
    return __builtin_bit_cast(float, hi ? (w & 0xFFFF0000u) : (w << 16));
}

// ---------------------------------------------------------------------------
// fp32 NCHW (64 ch) -> bf16 zero-padded NHWC [258][258][CDST], channels 0..63.
// If WRITE_G: also write group-major refg[b][g=cg][y][x][8ch] (unpadded).
// ---------------------------------------------------------------------------
template<int CDST, bool WRITE_G>
__global__ __launch_bounds__(256) void nchw_to_nhwc(
    const float* __restrict__ src, unsigned short* __restrict__ dst,
    unsigned short* __restrict__ dst_g)
{
    const int px = threadIdx.x, h = blockIdx.x, bi = blockIdx.y;
    const float* s = src + (size_t)bi * 64 * HWsz + (size_t)h * WW + px;
    unsigned short* d = dst + (((size_t)bi * PD + (h + 1)) * PD + (px + 1)) * CDST;
#pragma unroll
    for (int cg = 0; cg < 8; ++cg) {
        float v[8];
#pragma unroll
        for (int j = 0; j < 8; ++j) v[j] = s[(size_t)(cg * 8 + j) * HWsz];
        uint4 pk;
        pk.x = f2bf(v[0]) | ((unsigned)f2bf(v[1]) << 16);
        pk.y = f2bf(v[2]) | ((unsigned)f2bf(v[3]) << 16);
        pk.z = f2bf(v[4]) | ((unsigned)f2bf(v[5]) << 16);
        pk.w = f2bf(v[6]) | ((unsigned)f2bf(v[7]) << 16);
        *(uint4*)&d[cg * 8] = pk;
        if (WRITE_G) {
            unsigned short* dg = dst_g +
                (((size_t)(bi * 8 + cg) * HWsz) + (size_t)h * WW + px) * 8;
            *(uint4*)dg = pk;
        }
    }
}

// ---------------------------------------------------------------------------
// Zero the 1-px borders of the three padded NHWC buffers.
// ---------------------------------------------------------------------------
__global__ __launch_bounds__(256) void zero_border(
    unsigned short* __restrict__ p_off, unsigned short* __restrict__ p_cat,
    unsigned short* __restrict__ p_x1)
{
    const int bi = blockIdx.y, which = blockIdx.z;
    unsigned short* buf = which == 0 ? p_off : (which == 1 ? p_cat : p_x1);
    const int CIN = (which == 1) ? 128 : 64;
    const int NG = CIN / 8;
    unsigned short* p = buf + (size_t)bi * PD * PD * CIN;
    const int total = 1028 * 16;
    for (int i = blockIdx.x * 256 + threadIdx.x; i < total; i += gridDim.x * 256) {
        int g = i & 15;
        if (g >= NG) continue;
        int pxi = i >> 4;
        int r, c;
        if (pxi < 258)       { r = 0;   c = pxi; }
        else if (pxi < 516)  { r = 257; c = pxi - 258; }
        else if (pxi < 772)  { r = pxi - 516 + 1; c = 0; }
        else                 { r = pxi - 772 + 1; c = 257; }
        uint4 z = {0, 0, 0, 0};
        *(uint4*)&p[((size_t)r * PD + c) * CIN + g * 8] = z;
    }
}

// ---------------------------------------------------------------------------
// Fused weight packing, 32x32x16 A-frag order (unchanged formula):
// wpk[((cot*KST + kstep)*64 + lane)*8 + j]
//   co = cot*32 + (lane&31); tap = kstep/(Cin/16);
//   ci = (kstep%(Cin/16))*16 + (lane>>5)*8 + j.  Zero-pad co >= Cout.
// ---------------------------------------------------------------------------
__device__ inline void pack_one(const float* __restrict__ w, short* __restrict__ wpk,
                                int Cout, int Cin, int e)
{
    int j = e & 7;
    int lane = (e >> 3) & 63;
    int ksp = 9 * (Cin / 16);
    int kstep = (e >> 9) % ksp;
    int cot = (e >> 9) / ksp;
    int tap = kstep / (Cin / 16);
    int ci = (kstep % (Cin / 16)) * 16 + (lane >> 5) * 8 + j;
    int co = cot * 32 + (lane & 31);
    float v = (co < Cout) ? w[((size_t)co * Cin + ci) * 9 + tap] : 0.f;
    wpk[e] = (short)f2bf(v);
}

__global__ __launch_bounds__(256) void pack_all(
    const float* __restrict__ w1, short* __restrict__ d1,    // 144,64 : 110592
    const float* __restrict__ w2, short* __restrict__ d2,    // 64,128 :  73728
    const float* __restrict__ w3, short* __restrict__ d3)    // 64,64  :  36864
{
    int e = blockIdx.x * 256 + threadIdx.x;
    if (e < 110592)               pack_one(w1, d1, 144, 64, e);
    else if (e < 110592 + 73728)  pack_one(w2, d2, 64, 128, e - 110592);
    else if (e < 221184)          pack_one(w3, d3, 64, 64,  e - 184320);
}

// ---------------------------------------------------------------------------
// Implicit-GEMM 3x3 conv, bf16 MFMA 32x32x16 -- BARRIER-FREE version.
// Each of 4 waves owns 64 output px of one row and stages its own
// 3 rows x 66 px x 32 ci span into a PRIVATE LDS region, layout
// [row][ci-octet][66 px][8ci] (lane-linear 16B B-reads, conflict-free).
// No __syncthreads anywhere: waves pipeline against each other.
// COF co-fragments per wave (COF MFMAs per B-read).
// Grid: (256 rows, B*COTB).
// MODE 0: dst_bf = NHWC [256][256][144], guard co<144 (deform offsets)
// MODE 1: dst_bf = padded NHWC [258][258][64], ReLU (x1)
// MODE 2: dst_f  = NCHW fp32, ReLU + bf16 residual from resid_bf (p_cat)
// ---------------------------------------------------------------------------
template<int CIN, int COF, int COTB, int MODE, int MINW>
__global__ __launch_bounds__(256, MINW) void conv_mfma_nb(
    const unsigned short* __restrict__ src,
    const short* __restrict__ wpk,
    const float* __restrict__ bias,
    unsigned short* __restrict__ dst_bf,
    float* __restrict__ dst_f,
    const unsigned short* __restrict__ resid_bf)
{
    constexpr int CHUNKS = CIN / 32;
    constexpr int KST = 9 * (CIN / 16);
    constexpr int WSEG = 3 * 4 * 66 * 8;     // shorts per wave = 12672 B

    __shared__ unsigned short lds[4 * WSEG]; // 50,688 B

    const int tid  = threadIdx.x;
    const int lane = tid & 63;
    const int wv   = tid >> 6;
    const int half = lane >> 5;
    const int n32  = lane & 31;
    const int h  = blockIdx.x;
    const int bi = blockIdx.y / COTB;
    const int cb = blockIdx.y % COTB;
    const int cbase = cb * COF * 32;

    unsigned short* my = lds + wv * WSEG;
    const unsigned short* srcB = src + (size_t)bi * PD * PD * CIN;
    const short8* wbase = (const short8*)wpk;

    float16v acc[COF][2];
#pragma unroll
    for (int f = 0; f < COF; ++f) {
        float16v bv;
#pragma unroll
        for (int reg = 0; reg < 16; ++reg) {
            int co = cbase + f * 32 + (reg >> 2) * 8 + 4 * half + (reg & 3);
            float b = 0.f;
            if (MODE != 0 || co < 144) b = bias[co];
            bv[reg] = b;
        }
        acc[f][0] = bv;
        acc[f][1] = bv;
    }

    for (int ch = 0; ch < CHUNKS; ++ch) {
        // ---- wave-private staging: 3 rows x 66 px x 32 ci (4 octets) ----
        const unsigned short* gband = srcB + ((size_t)h * PD + wv * 64) * CIN + ch * 32;
#pragma unroll
        for (int i0 = 0; i0 < 264; i0 += 64) {
            int i = i0 + lane;
            if (i0 + 64 > 264 && i >= 264) continue;
            int px = i >> 2, o = i & 3;
#pragma unroll
            for (int r = 0; r < 3; ++r) {
                uint4 v = *(const uint4*)(gband + ((size_t)r * PD + px) * CIN + o * 8);
                *(uint4*)&my[(((size_t)r * 4 + o) * 66 + px) * 8] = v;
            }
        }
        // (no barrier: compiler inserts vmcnt/lgkmcnt waits for intra-wave RAW)

        // ---- MFMA over 9 taps x 2 ci-16-steps ----
#pragma unroll
        for (int tap = 0; tap < 9; ++tap) {
            const int row = tap / 3, dxo = tap % 3;
#pragma unroll
            for (int s = 0; s < 2; ++s) {
                const int kstep = tap * (CIN / 16) + ch * 2 + s;
                short8 a[COF];
#pragma unroll
                for (int f = 0; f < COF; ++f)
                    a[f] = wbase[((size_t)(cb * COF + f) * KST + kstep) * 64 + lane];
#pragma unroll
                for (int nt = 0; nt < 2; ++nt) {
                    short8 b = *(const short8*)
                        &my[(((size_t)row * 4 + s * 2 + half) * 66 + nt * 32 + dxo + n32) * 8];
#pragma unroll
                    for (int f = 0; f < COF; ++f)
                        acc[f][nt] = __builtin_amdgcn_mfma_f32_32x32x16_bf16(a[f], b, acc[f][nt], 0, 0, 0);
                }
            }
        }
    }

    // epilogue: C layout col = n32 (px), row = (reg&3) + 8*(reg>>2) + 4*half
#pragma unroll
    for (int f = 0; f < COF; ++f) {
#pragma unroll
        for (int nt = 0; nt < 2; ++nt) {
            const int px = wv * 64 + nt * 32 + n32;
            float16v a = acc[f][nt];
#pragma unroll
            for (int q = 0; q < 4; ++q) {
                const int co4 = cbase + f * 32 + q * 8 + 4 * half;
                float v0 = a[q * 4 + 0], v1 = a[q * 4 + 1];
                float v2 = a[q * 4 + 2], v3 = a[q * 4 + 3];
                if (MODE == 0) {
                    if (co4 < 144) {
                        unsigned short* d = dst_bf + (size_t)bi * HWsz * 144;
                        uint2 pk;
                        pk.x = f2bf(v0) | ((unsigned)f2bf(v1) << 16);
                        pk.y = f2bf(v2) | ((unsigned)f2bf(v3) << 16);
                        *(uint2*)&d[((size_t)h * WW + px) * 144 + co4] = pk;
                    }
                } else if (MODE == 1) {
                    unsigned short* d = dst_bf + (size_t)bi * PD * PD * 64;
                    uint2 pk;
                    pk.x = f2bf(fmaxf(v0, 0.f)) | ((unsigned)f2bf(fmaxf(v1, 0.f)) << 16);
                    pk.y = f2bf(fmaxf(v2, 0.f)) | ((unsigned)f2bf(fmaxf(v3, 0.f)) << 16);
                    *(uint2*)&d[(((size_t)h + 1) * PD + (px + 1)) * 64 + co4] = pk;
                } else {
                    const unsigned short* rp = resid_bf + (size_t)bi * PD * PD * 128;
                    uint2 rv = *(const uint2*)&rp[(((size_t)h + 1) * PD + (px + 1)) * 128 + 64 + co4];
                    float r0 = bfhalf(rv.x, 0), r1 = bfhalf(rv.x, 1);
                    float r2 = bfhalf(rv.y, 0), r3 = bfhalf(rv.y, 1);
                    float* d = dst_f + (size_t)bi * 64 * HWsz + (size_t)h * WW + px;
                    d[(size_t)(co4 + 0) * HWsz] = fmaxf(v0, 0.f) + r0;
                    d[(size_t)(co4 + 1) * HWsz] = fmaxf(v1, 0.f) + r1;
                    d[(size_t)(co4 + 2) * HWsz] = fmaxf(v2, 0.f) + r2;
                    d[(size_t)(co4 + 3) * HWsz] = fmaxf(v3, 0.f) + r3;
                }
            }
        }
    }
}

// ---------------------------------------------------------------------------
// Deformable conv v5 (unchanged from R5: 56 VGPR, 68 us, VALU-bound).
// ---------------------------------------------------------------------------
__global__ __launch_bounds__(256) void deform_k5(
    const unsigned short* __restrict__ refg,
    const unsigned short* __restrict__ doff,
    const float* __restrict__ wdef, const float* __restrict__ bdef,
    unsigned short* __restrict__ pcat_out)
{
    __shared__ float wsm2[576];    // [k][c][o]
    const int L = blockIdx.x;
    const int xcd = L & 7;
    const int j = L >> 3;
    const int g = j & 7;
    const int r = (j >> 3) & 31;
    const int bi = j >> 8;
    const int h = xcd * 32 + r;
    const int px = threadIdx.x;

    for (int i = threadIdx.x; i < 576; i += 256) {
        int o = i & 7, c = (i >> 3) & 7, k = i >> 6;
        wsm2[i] = wdef[(size_t)g * 576 + o * 72 + c * 9 + k];
    }
    __syncthreads();

    const unsigned int* dp = (const unsigned int*)(
        doff + (((size_t)bi * HWsz) + (size_t)h * WW + px) * 144 + g * 18);
    unsigned int dw[9];
#pragma unroll
    for (int k = 0; k < 9; ++k) dw[k] = dp[k];

    float acc[8];
#pragma unroll
    for (int o = 0; o < 8; ++o) acc[o] = bdef[g * 8 + o];

    const unsigned short* rb = refg + (size_t)(bi * 8 + g) * HWsz * 8;

#pragma unroll
    for (int k = 0; k < 9; ++k) {
        float dy = bfhalf(dw[k], 0);
        float dx = bfhalf(dw[k], 1);
        float py = dy + (float)(h + k / 3 - 1);
        float pxs = dx + (float)(px + k % 3 - 1);
        float fy = floorf(py), fx = floorf(pxs);
        int y0 = (int)fy, x0i = (int)fx;
        float ly = py - fy, lx = pxs - fx;
        int y1 = y0 + 1, x1i = x0i + 1;
        bool vy0 = (y0 >= 0) & (y0 < HH), vy1 = (y1 >= 0) & (y1 < HH);
        bool vx0 = (x0i >= 0) & (x0i < WW), vx1 = (x1i >= 0) & (x1i < WW);
        int cy0 = min(max(y0, 0), HH - 1), cy1 = min(max(y1, 0), HH - 1);
        int cx0 = min(max(x0i, 0), WW - 1), cx1 = min(max(x1i, 0), WW - 1);
        float w00 = (1.f - ly) * (1.f - lx), w01 = (1.f - ly) * lx;
        float w10 = ly * (1.f - lx), w11 = ly * lx;
        if (!(vy0 && vx0)) w00 = 0.f;
        if (!(vy0 && vx1)) w01 = 0.f;
        if (!(vy1 && vx0)) w10 = 0.f;
        if (!(vy1 && vx1)) w11 = 0.f;

        uint4 q00 = *(const uint4*)(rb + ((size_t)cy0 * WW + cx0) * 8);
        uint4 q01 = *(const uint4*)(rb + ((size_t)cy0 * WW + cx1) * 8);
        uint4 q10 = *(const uint4*)(rb + ((size_t)cy1 * WW + cx0) * 8);
        uint4 q11 = *(const uint4*)(rb + ((size_t)cy1 * WW + cx1) * 8);
        union U { uint4 v; unsigned int a[4]; };
        U u00{q00}, u01{q01}, u10{q10}, u11{q11};

#pragma unroll
        for (int cw = 0; cw < 4; ++cw) {
#pragma unroll
            for (int hl = 0; hl < 2; ++hl) {
                int c = cw * 2 + hl;
                float sv = w00 * bfhalf(u00.a[cw], hl) + w01 * bfhalf(u01.a[cw], hl)
                         + w10 * bfhalf(u10.a[cw], hl) + w11 * bfhalf(u11.a[cw], hl);
                const float* wp = &wsm2[((k * 8) + c) * 8];
                float4v wlo = *(const float4v*)wp;
                float4v whi = *(const float4v*)(wp + 4);
                acc[0] += wlo[0] * sv; acc[1] += wlo[1] * sv;
                acc[2] += wlo[2] * sv; acc[3] += wlo[3] * sv;
                acc[4] += whi[0] * sv; acc[5] += whi[1] * sv;
                acc[6] += whi[2] * sv; acc[7] += whi[3] * sv;
            }
        }
    }

    unsigned short* po = pcat_out + (((size_t)bi * PD + (h + 1)) * PD + (px + 1)) * 128 + 64 + g * 8;
    uint4 pk;
    pk.x = f2bf(acc[0]) | ((unsigned)f2bf(acc[1]) << 16);
    pk.y = f2bf(acc[2]) | ((unsigned)f2bf(acc[3]) << 16);
    pk.z = f2bf(acc[4]) | ((unsigned)f2bf(acc[5]) << 16);
    pk.w = f2bf(acc[6]) | ((unsigned)f2bf(acc[7]) << 16);
    *(uint4*)po = pk;
}

// ---------------------------------------------------------------------------
extern "C" void kernel_launch(void* const* d_in, const int* in_sizes, int n_in,
                              void* d_out, int out_size, void* d_ws, size_t ws_size,
                              hipStream_t stream)
{
    const float* offset = (const float*)d_in[0];
    const float* ref    = (const float*)d_in[1];
    const float* w_off  = (const float*)d_in[2];
    const float* b_off  = (const float*)d_in[3];
    const float* w_def  = (const float*)d_in[4];
    const float* b_def  = (const float*)d_in[5];
    const float* w_r1   = (const float*)d_in[6];
    const float* b_r1   = (const float*)d_in[7];
    const float* w_r2   = (const float*)d_in[8];
    const float* b_r2   = (const float*)d_in[9];
    float* out = (float*)d_out;

    // workspace layout (ushort elems)
    unsigned short* p_off = (unsigned short*)d_ws;          // 2*258*258*64   = 8,520,192
    unsigned short* p_cat = p_off + (size_t)8520192;        // 2*258*258*128  = 17,040,384
    unsigned short* p_x1  = p_cat + (size_t)17040384;       // 8,520,192
    unsigned short* doff  = p_x1 + (size_t)8520192;         // 2*256*256*144  = 18,874,368
    unsigned short* refg  = doff + (size_t)18874368;        // 2*8*65536*8    = 8,388,608
    short* wpk1  = (short*)(refg + (size_t)8388608);        // 110,592 (192co)
    short* wpkr1 = wpk1 + 110592;                           // 73,728
    short* wpkr2 = wpkr1 + 73728;                           // 36,864

    zero_border<<<dim3(65, 2, 3), 256, 0, stream>>>(p_off, p_cat, p_x1);

    pack_all<<<dim3((221184 + 255) / 256), 256, 0, stream>>>(
        w_off, wpk1, w_r1, wpkr1, w_r2, wpkr2);

    nchw_to_nhwc<64, false><<<dim3(256, 2), 256, 0, stream>>>(offset, p_off, nullptr);
    nchw_to_nhwc<128, true><<<dim3(256, 2), 256, 0, stream>>>(ref, p_cat, refg);

    // conv1: 64 -> 144 (padded 192): COF=3 (96 co/block), COTB=2
    conv_mfma_nb<64, 3, 2, 0, 2><<<dim3(256, 4), 256, 0, stream>>>(
        p_off, wpk1, b_off, doff, nullptr, nullptr);

    // deform (4096 linear blocks, XCD row-band swizzle)
    deform_k5<<<dim3(4096), 256, 0, stream>>>(refg, doff, w_def, b_def, p_cat);

    // r1: 128 -> 64, ReLU: COF=2, COTB=1
    conv_mfma_nb<128, 2, 1, 1, 3><<<dim3(256, 2), 256, 0, stream>>>(
        p_cat, wpkr1, b_r1, p_x1, nullptr, nullptr);

    // r2: 64 -> 64, ReLU + residual (bf16 from p_cat cols 64..127): COF=2
    conv_mfma_nb<64, 2, 1, 2, 3><<<dim3(256, 2), 256, 0, stream>>>(
        p_x1, wpkr2, b_r2, nullptr, out, p_cat);
}

// Round 7
// 341.030 us; speedup vs baseline: 1.0230x; 1.0230x over previous
//
#include <hip/hip_runtime.h>

typedef __attribute__((ext_vector_type(8)))  short  short8;
typedef __attribute__((ext_vector_type(4)))  float  float4v;
typedef __attribute__((ext_vector_type(16))) float  float16v;

constexpr int HH = 256, WW = 256;
constexpr int PD = 258;                 // padded spatial dim
constexpr size_t HWsz = (size_t)HH * WW;

__device__ inline unsigned short f2bf(float f) {
    unsigned int u = __builtin_bit_cast(unsigned int, f);
    u += 0x7FFFu + ((u >> 16) & 1u);
    return (unsigned short)(u >> 16);
}
__device__ inline float bfhalf(unsigned int w, int hi) {
    return __builtin_bit_cast(float, hi ? (w & 0xFFFF0000u) : (w << 16));
}

// ---------------------------------------------------------------------------
// fp32 NCHW (64 ch) -> bf16 zero-padded NHWC [258][258][CDST], channels 0..63.
// If WRITE_G: also write group-major refg[b][g=cg][y][x][8ch] (unpadded).
// ---------------------------------------------------------------------------
template<int CDST, bool WRITE_G>
__global__ __launch_bounds__(256) void nchw_to_nhwc(
    const float* __restrict__ src, unsigned short* __restrict__ dst,
    unsigned short* __restrict__ dst_g)
{
    const int px = threadIdx.x, h = blockIdx.x, bi = blockIdx.y;
    const float* s = src + (size_t)bi * 64 * HWsz + (size_t)h * WW + px;
    unsigned short* d = dst + (((size_t)bi * PD + (h + 1)) * PD + (px + 1)) * CDST;
#pragma unroll
    for (int cg = 0; cg < 8; ++cg) {
        float v[8];
#pragma unroll
        for (int j = 0; j < 8; ++j) v[j] = s[(size_t)(cg * 8 + j) * HWsz];
        uint4 pk;
        pk.x = f2bf(v[0]) | ((unsigned)f2bf(v[1]) << 16);
        pk.y = f2bf(v[2]) | ((unsigned)f2bf(v[3]) << 16);
        pk.z = f2bf(v[4]) | ((unsigned)f2bf(v[5]) << 16);
        pk.w = f2bf(v[6]) | ((unsigned)f2bf(v[7]) << 16);
        *(uint4*)&d[cg * 8] = pk;
        if (WRITE_G) {
            unsigned short* dg = dst_g +
                (((size_t)(bi * 8 + cg) * HWsz) + (size_t)h * WW + px) * 8;
            *(uint4*)dg = pk;
        }
    }
}

// ---------------------------------------------------------------------------
// Zero the 1-px borders of the three padded NHWC buffers.
// ---------------------------------------------------------------------------
__global__ __launch_bounds__(256) void zero_border(
    unsigned short* __restrict__ p_off, unsigned short* __restrict__ p_cat,
    unsigned short* __restrict__ p_x1)
{
    const int bi = blockIdx.y, which = blockIdx.z;
    unsigned short* buf = which == 0 ? p_off : (which == 1 ? p_cat : p_x1);
    const int CIN = (which == 1) ? 128 : 64;
    const int NG = CIN / 8;
    unsigned short* p = buf + (size_t)bi * PD * PD * CIN;
    const int total = 1028 * 16;
    for (int i = blockIdx.x * 256 + threadIdx.x; i < total; i += gridDim.x * 256) {
        int g = i & 15;
        if (g >= NG) continue;
        int pxi = i >> 4;
        int r, c;
        if (pxi < 258)       { r = 0;   c = pxi; }
        else if (pxi < 516)  { r = 257; c = pxi - 258; }
        else if (pxi < 772)  { r = pxi - 516 + 1; c = 0; }
        else                 { r = pxi - 772 + 1; c = 257; }
        uint4 z = {0, 0, 0, 0};
        *(uint4*)&p[((size_t)r * PD + c) * CIN + g * 8] = z;
    }
}

// ---------------------------------------------------------------------------
// Fused weight packing, 32x32x16 A-frag order:
// wpk[((cot*KST + kstep)*64 + lane)*8 + j]
//   co = cot*32 + (lane&31); tap = kstep/(Cin/16);
//   ci = (kstep%(Cin/16))*16 + (lane>>5)*8 + j.  Zero-pad co >= Cout.
// ---------------------------------------------------------------------------
__device__ inline void pack_one(const float* __restrict__ w, short* __restrict__ wpk,
                                int Cout, int Cin, int e)
{
    int j = e & 7;
    int lane = (e >> 3) & 63;
    int ksp = 9 * (Cin / 16);
    int kstep = (e >> 9) % ksp;
    int cot = (e >> 9) / ksp;
    int tap = kstep / (Cin / 16);
    int ci = (kstep % (Cin / 16)) * 16 + (lane >> 5) * 8 + j;
    int co = cot * 32 + (lane & 31);
    float v = (co < Cout) ? w[((size_t)co * Cin + ci) * 9 + tap] : 0.f;
    wpk[e] = (short)f2bf(v);
}

__global__ __launch_bounds__(256) void pack_all(
    const float* __restrict__ w1, short* __restrict__ d1,    // 144,64 : 110592
    const float* __restrict__ w2, short* __restrict__ d2,    // 64,128 :  73728
    const float* __restrict__ w3, short* __restrict__ d3)    // 64,64  :  36864
{
    int e = blockIdx.x * 256 + threadIdx.x;
    if (e < 110592)               pack_one(w1, d1, 144, 64, e);
    else if (e < 110592 + 73728)  pack_one(w2, d2, 64, 128, e - 110592);
    else if (e < 221184)          pack_one(w3, d3, 64, 64,  e - 184320);
}

// ---------------------------------------------------------------------------
// Implicit-GEMM 3x3 conv, bf16 MFMA 32x32x16, barrier-free wave-private
// staging.  COF=2 everywhere, MINW=3 (bounded VGPR -> 3 waves/SIMD).
// Grid: (256 rows, B*COTB).
// MODE 0: dst_bf = NHWC [256][256][144], guard co<144 (deform offsets)
// MODE 1: dst_bf = padded NHWC [258][258][64], ReLU (x1)
// MODE 2: dst_f  = NCHW fp32, ReLU + bf16 residual from resid_bf (p_cat)
// ---------------------------------------------------------------------------
template<int CIN, int COF, int COTB, int MODE, int MINW>
__global__ __launch_bounds__(256, MINW) void conv_mfma_nb(
    const unsigned short* __restrict__ src,
    const short* __restrict__ wpk,
    const float* __restrict__ bias,
    unsigned short* __restrict__ dst_bf,
    float* __restrict__ dst_f,
    const unsigned short* __restrict__ resid_bf)
{
    constexpr int CHUNKS = CIN / 32;
    constexpr int KST = 9 * (CIN / 16);
    constexpr int WSEG = 3 * 4 * 66 * 8;     // shorts per wave = 12672 B

    __shared__ unsigned short lds[4 * WSEG]; // 50,688 B

    const int tid  = threadIdx.x;
    const int lane = tid & 63;
    const int wv   = tid >> 6;
    const int half = lane >> 5;
    const int n32  = lane & 31;
    const int h  = blockIdx.x;
    const int bi = blockIdx.y / COTB;
    const int cb = blockIdx.y % COTB;
    const int cbase = cb * COF * 32;

    unsigned short* my = lds + wv * WSEG;
    const unsigned short* srcB = src + (size_t)bi * PD * PD * CIN;
    const short8* wbase = (const short8*)wpk;

    float16v acc[COF][2];
#pragma unroll
    for (int f = 0; f < COF; ++f) {
        float16v bv;
#pragma unroll
        for (int reg = 0; reg < 16; ++reg) {
            int co = cbase + f * 32 + (reg >> 2) * 8 + 4 * half + (reg & 3);
            float b = 0.f;
            if (MODE != 0 || co < 144) b = bias[co];
            bv[reg] = b;
        }
        acc[f][0] = bv;
        acc[f][1] = bv;
    }

    for (int ch = 0; ch < CHUNKS; ++ch) {
        // ---- wave-private staging: 3 rows x 66 px x 32 ci (4 octets) ----
        const unsigned short* gband = srcB + ((size_t)h * PD + wv * 64) * CIN + ch * 32;
#pragma unroll
        for (int i0 = 0; i0 < 264; i0 += 64) {
            int i = i0 + lane;
            if (i0 + 64 > 264 && i >= 264) continue;
            int px = i >> 2, o = i & 3;
#pragma unroll
            for (int r = 0; r < 3; ++r) {
                uint4 v = *(const uint4*)(gband + ((size_t)r * PD + px) * CIN + o * 8);
                *(uint4*)&my[(((size_t)r * 4 + o) * 66 + px) * 8] = v;
            }
        }

        // ---- MFMA over 9 taps x 2 ci-16-steps ----
#pragma unroll
        for (int tap = 0; tap < 9; ++tap) {
            const int row = tap / 3, dxo = tap % 3;
#pragma unroll
            for (int s = 0; s < 2; ++s) {
                const int kstep = tap * (CIN / 16) + ch * 2 + s;
                short8 a[COF];
#pragma unroll
                for (int f = 0; f < COF; ++f)
                    a[f] = wbase[((size_t)(cb * COF + f) * KST + kstep) * 64 + lane];
#pragma unroll
                for (int nt = 0; nt < 2; ++nt) {
                    short8 b = *(const short8*)
                        &my[(((size_t)row * 4 + s * 2 + half) * 66 + nt * 32 + dxo + n32) * 8];
#pragma unroll
                    for (int f = 0; f < COF; ++f)
                        acc[f][nt] = __builtin_amdgcn_mfma_f32_32x32x16_bf16(a[f], b, acc[f][nt], 0, 0, 0);
                }
            }
        }
    }

    // epilogue: C layout col = n32 (px), row = (reg&3) + 8*(reg>>2) + 4*half
#pragma unroll
    for (int f = 0; f < COF; ++f) {
#pragma unroll
        for (int nt = 0; nt < 2; ++nt) {
            const int px = wv * 64 + nt * 32 + n32;
            float16v a = acc[f][nt];
#pragma unroll
            for (int q = 0; q < 4; ++q) {
                const int co4 = cbase + f * 32 + q * 8 + 4 * half;
                float v0 = a[q * 4 + 0], v1 = a[q * 4 + 1];
                float v2 = a[q * 4 + 2], v3 = a[q * 4 + 3];
                if (MODE == 0) {
                    if (co4 < 144) {
                        unsigned short* d = dst_bf + (size_t)bi * HWsz * 144;
                        uint2 pk;
                        pk.x = f2bf(v0) | ((unsigned)f2bf(v1) << 16);
                        pk.y = f2bf(v2) | ((unsigned)f2bf(v3) << 16);
                        *(uint2*)&d[((size_t)h * WW + px) * 144 + co4] = pk;
                    }
                } else if (MODE == 1) {
                    unsigned short* d = dst_bf + (size_t)bi * PD * PD * 64;
                    uint2 pk;
                    pk.x = f2bf(fmaxf(v0, 0.f)) | ((unsigned)f2bf(fmaxf(v1, 0.f)) << 16);
                    pk.y = f2bf(fmaxf(v2, 0.f)) | ((unsigned)f2bf(fmaxf(v3, 0.f)) << 16);
                    *(uint2*)&d[(((size_t)h + 1) * PD + (px + 1)) * 64 + co4] = pk;
                } else {
                    const unsigned short* rp = resid_bf + (size_t)bi * PD * PD * 128;
                    uint2 rv = *(const uint2*)&rp[(((size_t)h + 1) * PD + (px + 1)) * 128 + 64 + co4];
                    float r0 = bfhalf(rv.x, 0), r1 = bfhalf(rv.x, 1);
                    float r2 = bfhalf(rv.y, 0), r3 = bfhalf(rv.y, 1);
                    float* d = dst_f + (size_t)bi * 64 * HWsz + (size_t)h * WW + px;
                    d[(size_t)(co4 + 0) * HWsz] = fmaxf(v0, 0.f) + r0;
                    d[(size_t)(co4 + 1) * HWsz] = fmaxf(v1, 0.f) + r1;
                    d[(size_t)(co4 + 2) * HWsz] = fmaxf(v2, 0.f) + r2;
                    d[(size_t)(co4 + 3) * HWsz] = fmaxf(v3, 0.f) + r3;
                }
            }
        }
    }
}

// ---------------------------------------------------------------------------
// Deformable conv v6: R5 structure (56 VGPR) with float2-packed acc update
// (4 packed FMAs replace 8 scalar FMAs in the inner einsum).
// ---------------------------------------------------------------------------
__global__ __launch_bounds__(256) void deform_k6(
    const unsigned short* __restrict__ refg,
    const unsigned short* __restrict__ doff,
    const float* __restrict__ wdef, const float* __restrict__ bdef,
    unsigned short* __restrict__ pcat_out)
{
    __shared__ float wsm2[576];    // [k][c][o]  (o pairs read as float2)
    const int L = blockIdx.x;
    const int xcd = L & 7;
    const int j = L >> 3;
    const int g = j & 7;
    const int r = (j >> 3) & 31;
    const int bi = j >> 8;
    const int h = xcd * 32 + r;
    const int px = threadIdx.x;

    for (int i = threadIdx.x; i < 576; i += 256) {
        int o = i & 7, c = (i >> 3) & 7, k = i >> 6;
        wsm2[i] = wdef[(size_t)g * 576 + o * 72 + c * 9 + k];
    }
    __syncthreads();

    const unsigned int* dp = (const unsigned int*)(
        doff + (((size_t)bi * HWsz) + (size_t)h * WW + px) * 144 + g * 18);
    unsigned int dw[9];
#pragma unroll
    for (int k = 0; k < 9; ++k) dw[k] = dp[k];

    float2 acc2[4];
#pragma unroll
    for (int o = 0; o < 4; ++o)
        acc2[o] = make_float2(bdef[g * 8 + 2 * o], bdef[g * 8 + 2 * o + 1]);

    const unsigned short* rb = refg + (size_t)(bi * 8 + g) * HWsz * 8;

#pragma unroll
    for (int k = 0; k < 9; ++k) {
        float dy = bfhalf(dw[k], 0);
        float dx = bfhalf(dw[k], 1);
        float py = dy + (float)(h + k / 3 - 1);
        float pxs = dx + (float)(px + k % 3 - 1);
        float fy = floorf(py), fx = floorf(pxs);
        int y0 = (int)fy, x0i = (int)fx;
        float ly = py - fy, lx = pxs - fx;
        int y1 = y0 + 1, x1i = x0i + 1;
        bool vy0 = (y0 >= 0) & (y0 < HH), vy1 = (y1 >= 0) & (y1 < HH);
        bool vx0 = (x0i >= 0) & (x0i < WW), vx1 = (x1i >= 0) & (x1i < WW);
        int cy0 = min(max(y0, 0), HH - 1), cy1 = min(max(y1, 0), HH - 1);
        int cx0 = min(max(x0i, 0), WW - 1), cx1 = min(max(x1i, 0), WW - 1);
        float w00 = (1.f - ly) * (1.f - lx), w01 = (1.f - ly) * lx;
        float w10 = ly * (1.f - lx), w11 = ly * lx;
        if (!(vy0 && vx0)) w00 = 0.f;
        if (!(vy0 && vx1)) w01 = 0.f;
        if (!(vy1 && vx0)) w10 = 0.f;
        if (!(vy1 && vx1)) w11 = 0.f;

        uint4 q00 = *(const uint4*)(rb + ((size_t)cy0 * WW + cx0) * 8);
        uint4 q01 = *(const uint4*)(rb + ((size_t)cy0 * WW + cx1) * 8);
        uint4 q10 = *(const uint4*)(rb + ((size_t)cy1 * WW + cx0) * 8);
        uint4 q11 = *(const uint4*)(rb + ((size_t)cy1 * WW + cx1) * 8);
        union U { uint4 v; unsigned int a[4]; };
        U u00{q00}, u01{q01}, u10{q10}, u11{q11};

#pragma unroll
        for (int cw = 0; cw < 4; ++cw) {
#pragma unroll
            for (int hl = 0; hl < 2; ++hl) {
                int c = cw * 2 + hl;
                float sv = w00 * bfhalf(u00.a[cw], hl) + w01 * bfhalf(u01.a[cw], hl)
                         + w10 * bfhalf(u10.a[cw], hl) + w11 * bfhalf(u11.a[cw], hl);
                const float2* wp2 = (const float2*)&wsm2[((k * 8) + c) * 8];
#pragma unroll
                for (int o = 0; o < 4; ++o) {
                    acc2[o].x = fmaf(wp2[o].x, sv, acc2[o].x);
                    acc2[o].y = fmaf(wp2[o].y, sv, acc2[o].y);
                }
            }
        }
    }

    unsigned short* po = pcat_out + (((size_t)bi * PD + (h + 1)) * PD + (px + 1)) * 128 + 64 + g * 8;
    uint4 pk;
    pk.x = f2bf(acc2[0].x) | ((unsigned)f2bf(acc2[0].y) << 16);
    pk.y = f2bf(acc2[1].x) | ((unsigned)f2bf(acc2[1].y) << 16);
    pk.z = f2bf(acc2[2].x) | ((unsigned)f2bf(acc2[2].y) << 16);
    pk.w = f2bf(acc2[3].x) | ((unsigned)f2bf(acc2[3].y) << 16);
    *(uint4*)po = pk;
}

// ---------------------------------------------------------------------------
extern "C" void kernel_launch(void* const* d_in, const int* in_sizes, int n_in,
                              void* d_out, int out_size, void* d_ws, size_t ws_size,
                              hipStream_t stream)
{
    const float* offset = (const float*)d_in[0];
    const float* ref    = (const float*)d_in[1];
    const float* w_off  = (const float*)d_in[2];
    const float* b_off  = (const float*)d_in[3];
    const float* w_def  = (const float*)d_in[4];
    const float* b_def  = (const float*)d_in[5];
    const float* w_r1   = (const float*)d_in[6];
    const float* b_r1   = (const float*)d_in[7];
    const float* w_r2   = (const float*)d_in[8];
    const float* b_r2   = (const float*)d_in[9];
    float* out = (float*)d_out;

    // workspace layout (ushort elems)
    unsigned short* p_off = (unsigned short*)d_ws;          // 2*258*258*64   = 8,520,192
    unsigned short* p_cat = p_off + (size_t)8520192;        // 2*258*258*128  = 17,040,384
    unsigned short* p_x1  = p_cat + (size_t)17040384;       // 8,520,192
    unsigned short* doff  = p_x1 + (size_t)8520192;         // 2*256*256*144  = 18,874,368
    unsigned short* refg  = doff + (size_t)18874368;        // 2*8*65536*8    = 8,388,608
    short* wpk1  = (short*)(refg + (size_t)8388608);        // 110,592 (192co)
    short* wpkr1 = wpk1 + 110592;                           // 73,728
    short* wpkr2 = wpkr1 + 73728;                           // 36,864

    zero_border<<<dim3(65, 2, 3), 256, 0, stream>>>(p_off, p_cat, p_x1);

    pack_all<<<dim3((221184 + 255) / 256), 256, 0, stream>>>(
        w_off, wpk1, w_r1, wpkr1, w_r2, wpkr2);

    nchw_to_nhwc<64, false><<<dim3(256, 2), 256, 0, stream>>>(offset, p_off, nullptr);
    nchw_to_nhwc<128, true><<<dim3(256, 2), 256, 0, stream>>>(ref, p_cat, refg);

    // conv1: 64 -> 144 (padded 192): COF=2 (64 co/block), COTB=3
    conv_mfma_nb<64, 2, 3, 0, 3><<<dim3(256, 6), 256, 0, stream>>>(
        p_off, wpk1, b_off, doff, nullptr, nullptr);

    // deform (4096 linear blocks, XCD row-band swizzle)
    deform_k6<<<dim3(4096), 256, 0, stream>>>(refg, doff, w_def, b_def, p_cat);

    // r1: 128 -> 64, ReLU: COF=2, COTB=1
    conv_mfma_nb<128, 2, 1, 1, 3><<<dim3(256, 2), 256, 0, stream>>>(
        p_cat, wpkr1, b_r1, p_x1, nullptr, nullptr);

    // r2: 64 -> 64, ReLU + residual (bf16 from p_cat cols 64..127): COF=2
    conv_mfma_nb<64, 2, 1, 2, 3><<<dim3(256, 2), 256, 0, stream>>>(
        p_x1, wpkr2, b_r2, nullptr, out, p_cat);
}